// Round 6
// baseline (1317.448 us; speedup 1.0000x reference)
//
#include <hip/hip_runtime.h>
#include <hip/hip_bf16.h>
#include <hip/hip_fp8.h>
#include <stdint.h>

#define B_      8
#define GRID_   24
#define C_      768
#define NPATCH  (B_*GRID_*GRID_)   // 4608
#define PRE     1024
#define TGT     1024
#define NMEM    20000
#define NMEM_PAD 20096             // 157 * 128
#define IMG_    384
#define SEQ     577                // GRID*GRID + 1

typedef int   intx4  __attribute__((ext_vector_type(4)));
typedef int   intx8  __attribute__((ext_vector_type(8)));
typedef float floatx4 __attribute__((ext_vector_type(4)));

// ---------------------------------------------------------------------------
// Kernel PREP (fused): blocks [0,NPATCH) = per-patch pooled embedding -> fp8
// e4m3 + ||e_q||^2 + psbits seed; blocks [NPATCH, ...) = memory_bank fp32 ->
// fp8 + ||m_q||^2 (4 rows/block, one wave/row).
// ---------------------------------------------------------------------------
__global__ __launch_bounds__(256) void prep_kernel(
    const float* __restrict__ f6, const float* __restrict__ f8,
    const float* __restrict__ f10, const float* __restrict__ mb,
    uint8_t* __restrict__ emb, float* __restrict__ enorm,
    uint8_t* __restrict__ mq, float* __restrict__ mnorm,
    int* __restrict__ psbits)
{
    __shared__ float pooled[3*PRE];   // 12 KB (emb half only)
    __shared__ float red[4];
    const int t = threadIdx.x;

    if (blockIdx.x < NPATCH) {
        // ---- embedding half ----
        const int n   = blockIdx.x;
        const int b   = n / (GRID_*GRID_);
        const int yx  = n - b*(GRID_*GRID_);
        const int y   = yx / GRID_;
        const int x   = yx - y*GRID_;

        if (t == 0) psbits[n] = 0x7f7f7f7f;   // +huge float bits for atomicMin

        const float* fl[3] = {f6, f8, f10};
#pragma unroll
        for (int l = 0; l < 3; ++l) {
            const float* f = fl[l];
            float A0 = 0.f, B0 = 0.f, C1 = 0.f, D1 = 0.f, E2 = 0.f, F2 = 0.f;
#pragma unroll
            for (int k = 0; k < 9; ++k) {
                const int kh = k / 3, kw = k - kh*3;
                const int ny = y + kh - 1, nx = x + kw - 1;
                const bool v = (ny >= 0 && ny < GRID_ && nx >= 0 && nx < GRID_);
                const int off = v ? (b*SEQ + 1 + ny*GRID_ + nx) : (b*SEQ);
                const float* p = f + (size_t)off*C_ + 3*t;
                float a = p[0], bq = p[1], c = p[2];
                if (!v) { a = 0.f; bq = 0.f; c = 0.f; }
                if (k <= 6) A0 += a;
                if (k >= 6) B0 += a;
                if (k <= 4) C1 += bq;
                if (k >= 4) D1 += bq;
                if (k <= 2) E2 += c;
                if (k >= 2) F2 += c;
            }
            float4 pv;
            pv.x = A0 * (1.f/7.f);
            pv.y = (B0 + C1) * (1.f/8.f);
            pv.z = (D1 + E2) * (1.f/8.f);
            pv.w = F2 * (1.f/7.f);
            *(float4*)(pooled + l*PRE + 4*t) = pv;
        }
        __syncthreads();

        // Aggregator + fp8 quantization; norm from QUANTIZED values so that
        // d2 = ||e_q||^2 + ||m_q||^2 - 2 e_q.m_q == ||e_q - m_q||^2 exactly
        float psq = 0.f;
        unsigned ob = 0;
#pragma unroll
        for (int r = 0; r < 4; ++r) {
            const int j = 4*t + r;
            float vv = (pooled[3*j] + pooled[3*j+1] + pooled[3*j+2]) * (1.f/3.f);
            __hip_fp8_e4m3 q(vv);
            ob |= ((unsigned)q.__x) << (8*r);
            float dq = (float)q;
            psq += dq*dq;
        }
        *(unsigned*)(emb + (size_t)n*TGT + 4*t) = ob;

        for (int off = 32; off > 0; off >>= 1) psq += __shfl_down(psq, off, 64);
        if ((t & 63) == 0) red[t >> 6] = psq;
        __syncthreads();
        if (t == 0) enorm[n] = (red[0] + red[1]) + (red[2] + red[3]);
    } else {
        // ---- memory-bank half ----
        const int r = (blockIdx.x - NPATCH)*4 + (t >> 6);
        const int l = t & 63;
        float psq = 0.f;
        unsigned ow[4];
        if (r < NMEM) {
            const float4* src = (const float4*)(mb + (size_t)r*TGT) + l*4;
#pragma unroll
            for (int i = 0; i < 4; ++i) {
                float4 v = src[i];
                __hip_fp8_e4m3 q0(v.x), q1(v.y), q2(v.z), q3(v.w);
                ow[i] = (unsigned)q0.__x | ((unsigned)q1.__x << 8)
                      | ((unsigned)q2.__x << 16) | ((unsigned)q3.__x << 24);
                float d0 = (float)q0, d1 = (float)q1, d2 = (float)q2, d3 = (float)q3;
                psq += d0*d0 + d1*d1 + d2*d2 + d3*d3;
            }
        } else {
            ow[0] = ow[1] = ow[2] = ow[3] = 0u;
        }
        *(uint4*)(mq + (size_t)r*TGT + l*16) = make_uint4(ow[0], ow[1], ow[2], ow[3]);

        for (int off = 32; off > 0; off >>= 1) psq += __shfl_down(psq, off, 64);
        if (l == 0) mnorm[r] = (r < NMEM) ? psq : 1e30f;
    }
}

// ---------------------------------------------------------------------------
// Kernel B: fused fp8 GEMM + min.  MX-scaled MFMA 16x16x128, unit scales.
// 128x128 tile, BK=128, XOR-swizzled LDS (16B chunk c of row r at slot
// c ^ (r&7)).
// v6 register budget: 256 threads, 4 waves of 64x64 (acc[4][4]=64) +
// b[4]=32 + one live a=8 + ~30 addressing ≈ 135 live.
// __launch_bounds__(256,3): cap = 512/3 ≈ 170 regs/wave under BOTH readings
// of the 2nd arg (3 waves/EU, or 3 blocks/CU of 256) -> headroom, no spill.
// R4 (256,4 -> cap 128) and R5 (512,4 -> resolved to cap 64) both spilled
// acc to scratch every K-iter (2.2-2.4 GB WRITE_SIZE).
// ---------------------------------------------------------------------------
__device__ __forceinline__ void load_lds16(const void* g, void* l)
{
    __builtin_amdgcn_global_load_lds(
        (__attribute__((address_space(1))) void*)g,
        (__attribute__((address_space(3))) void*)l, 16, 0, 0);
}

__device__ __forceinline__ intx8 read_frag(const uint8_t* base, int row, int g)
{
    const int s0 = (2*g) ^ (row & 7);                 // chunk 2g   -> slot s0
    const intx4 lo = *(const intx4*)(base + row*128 + s0*16);
    const intx4 hi = *(const intx4*)(base + row*128 + (s0^1)*16); // chunk 2g+1
    intx8 r;
    r[0]=lo[0]; r[1]=lo[1]; r[2]=lo[2]; r[3]=lo[3];
    r[4]=hi[0]; r[5]=hi[1]; r[6]=hi[2]; r[7]=hi[3];
    return r;
}

__global__ __launch_bounds__(256, 3) void nnmin_kernel(
    const uint8_t* __restrict__ E, const uint8_t* __restrict__ M,
    const float* __restrict__ enorm, const float* __restrict__ mnorm,
    int* __restrict__ out_min)
{
    __shared__ __attribute__((aligned(16))) uint8_t As[128*128];  // 16 KB
    __shared__ __attribute__((aligned(16))) uint8_t Bs[128*128];  // 16 KB

    const int m0   = blockIdx.x * 128;
    const int n0   = blockIdx.y * 128;
    const int tid  = threadIdx.x;
    const int wave = tid >> 6;        // 0..3
    const int lane = tid & 63;
    const int wm   = wave >> 1;       // 0..1 : 64-row half
    const int wn   = wave & 1;        // 0..1 : 64-col half

    // staging: each wave stages 32 rows of A and 32 rows of B per K-iter,
    // in 4 calls of 8 rows (64 lanes x 16B = 8 rows x 128B each).
    const int sr8 = lane >> 3;                  // row within 8-row group
    const int sch = ((lane & 7) ^ sr8) * 16;    // swizzled global chunk
    const uint8_t* gA = E + (size_t)(m0 + wave*32 + sr8)*TGT + sch;
    const uint8_t* gB = M + (size_t)(n0 + wave*32 + sr8)*TGT + sch;
    uint8_t* lA = As + wave*32*128 + lane*16;
    uint8_t* lB = Bs + wave*32*128 + lane*16;

    floatx4 acc[4][4];
#pragma unroll
    for (int i = 0; i < 4; ++i)
#pragma unroll
        for (int j = 0; j < 4; ++j) acc[i][j] = (floatx4)0.0f;

    const int fr = lane & 15;       // fragment row within 16
    const int fg = lane >> 4;       // k-group: k = fg*32 + 0..31

    for (int k0 = 0; k0 < TGT; k0 += 128) {
#pragma unroll
        for (int q = 0; q < 4; ++q) {
            load_lds16(gA + (size_t)q*8*TGT + k0, lA + q*8*128);
            load_lds16(gB + (size_t)q*8*TGT + k0, lB + q*8*128);
        }
        __syncthreads();

        intx8 b[4];
#pragma unroll
        for (int tn = 0; tn < 4; ++tn)
            b[tn] = read_frag(Bs, wn*64 + tn*16 + fr, fg);
#pragma unroll
        for (int tm = 0; tm < 4; ++tm) {
            const intx8 a = read_frag(As, wm*64 + tm*16 + fr, fg);
#pragma unroll
            for (int tn = 0; tn < 4; ++tn)
                acc[tm][tn] = __builtin_amdgcn_mfma_scale_f32_16x16x128_f8f6f4(
                    a, b[tn], acc[tm][tn],
                    0 /*cbsz: A=fp8*/, 0 /*blgp: B=fp8*/,
                    0, 0x7f7f7f7f /*scale_a = 1.0*/,
                    0, 0x7f7f7f7f /*scale_b = 1.0*/);
        }
        __syncthreads();
    }

    // epilogue: d2 + min over this block's 128 columns, atomicMin per row
    const int col  = lane & 15;
    const int rowq = (lane >> 4) * 4;
    const int colbase = n0 + wn*64;
    float mn[4];
#pragma unroll
    for (int tn = 0; tn < 4; ++tn) mn[tn] = mnorm[colbase + tn*16 + col];
#pragma unroll
    for (int tm = 0; tm < 4; ++tm) {
        const floatx4 en4 = *(const floatx4*)(enorm + m0 + wm*64 + tm*16 + rowq);
#pragma unroll
        for (int r = 0; r < 4; ++r) {
            float en = en4[r];
            float best = 1e38f;
#pragma unroll
            for (int tn = 0; tn < 4; ++tn) {
                float d2 = en + mn[tn] - 2.0f * acc[tm][tn][r];
                best = fminf(best, d2);
            }
#pragma unroll
            for (int off = 1; off < 16; off <<= 1)
                best = fminf(best, __shfl_xor(best, off, 64));
            if (col == 0)
                atomicMin(&out_min[m0 + wm*64 + tm*16 + rowq + r],
                          __float_as_int(best));
        }
    }
}

// ---------------------------------------------------------------------------
// Kernel POST (fused): blocks [0,4608) = bilinear 24->384 mask upsample
// (jax half-pixel == clamped bilinear); blocks [4608,4616) = per-image max.
// ---------------------------------------------------------------------------
__global__ __launch_bounds__(256) void post_kernel(
    const int* __restrict__ ps_bits, float* __restrict__ scores,
    float* __restrict__ masks)
{
    if (blockIdx.x < (B_*IMG_*IMG_)/256) {
        int idx = blockIdx.x*256 + threadIdx.x;
        int b  = idx / (IMG_*IMG_);
        int p  = idx - b*(IMG_*IMG_);
        int oy = p / IMG_, ox = p - oy*IMG_;

        float fy = (oy + 0.5f) * (1.0f/16.0f) - 0.5f;
        float fx = (ox + 0.5f) * (1.0f/16.0f) - 0.5f;
        int y0 = (int)floorf(fy); float ty = fy - (float)y0;
        int x0 = (int)floorf(fx); float tx = fx - (float)x0;
        int y0c = min(max(y0, 0), GRID_-1), y1c = min(max(y0+1, 0), GRID_-1);
        int x0c = min(max(x0, 0), GRID_-1), x1c = min(max(x0+1, 0), GRID_-1);

        const int* psb = ps_bits + b*GRID_*GRID_;
        float v00 = __int_as_float(psb[y0c*GRID_ + x0c]);
        float v01 = __int_as_float(psb[y0c*GRID_ + x1c]);
        float v10 = __int_as_float(psb[y1c*GRID_ + x0c]);
        float v11 = __int_as_float(psb[y1c*GRID_ + x1c]);
        float v0 = v00 + (v01 - v00)*tx;
        float v1 = v10 + (v11 - v10)*tx;
        masks[idx] = v0 + (v1 - v0)*ty;
    } else {
        const int b = blockIdx.x - (B_*IMG_*IMG_)/256;
        const int tid = threadIdx.x;
        __shared__ float red[4];
        float m = -1e38f;
        for (int i = tid; i < GRID_*GRID_; i += 256)
            m = fmaxf(m, __int_as_float(ps_bits[b*GRID_*GRID_ + i]));
        for (int off = 32; off > 0; off >>= 1)
            m = fmaxf(m, __shfl_down(m, off, 64));
        if ((tid & 63) == 0) red[tid >> 6] = m;
        __syncthreads();
        if (tid == 0)
            scores[b] = fmaxf(fmaxf(red[0], red[1]), fmaxf(red[2], red[3]));
    }
}

// ---------------------------------------------------------------------------
extern "C" void kernel_launch(void* const* d_in, const int* in_sizes, int n_in,
                              void* d_out, int out_size, void* d_ws, size_t ws_size,
                              hipStream_t stream)
{
    const float* f6  = (const float*)d_in[0];
    const float* f8  = (const float*)d_in[1];
    const float* f10 = (const float*)d_in[2];
    const float* mb  = (const float*)d_in[3];
    float* out = (float*)d_out;

    char* ws = (char*)d_ws;
    uint8_t* emb = (uint8_t*)ws; ws += (size_t)NPATCH*TGT;       // 4.7 MB
    uint8_t* mq  = (uint8_t*)ws; ws += (size_t)NMEM_PAD*TGT;     // 20.6 MB
    float* enorm = (float*)ws;   ws += (size_t)NPATCH*sizeof(float);
    float* mnorm = (float*)ws;   ws += (size_t)NMEM_PAD*sizeof(float);
    int* psbits  = (int*)ws;     ws += (size_t)NPATCH*sizeof(int);

    hipLaunchKernelGGL(prep_kernel, dim3(NPATCH + NMEM_PAD/4), dim3(256), 0,
                       stream, f6, f8, f10, mb, emb, enorm, mq, mnorm, psbits);
    hipLaunchKernelGGL(nnmin_kernel, dim3(NPATCH/128, NMEM_PAD/128), dim3(256),
                       0, stream, emb, mq, enorm, mnorm, psbits);
    hipLaunchKernelGGL(post_kernel, dim3((B_*IMG_*IMG_)/256 + B_), dim3(256),
                       0, stream, psbits, out, out + B_);
}

// Round 7
// 1158.209 us; speedup vs baseline: 1.1375x; 1.1375x over previous
//
#include <hip/hip_runtime.h>
#include <hip/hip_bf16.h>
#include <hip/hip_fp8.h>
#include <stdint.h>

#define B_      8
#define GRID_   24
#define C_      768
#define NPATCH  (B_*GRID_*GRID_)   // 4608
#define PRE     1024
#define TGT     1024
#define NMEM    20000
#define NMEM_PAD 20096             // 157 * 128
#define IMG_    384
#define SEQ     577                // GRID*GRID + 1

typedef int   intx4  __attribute__((ext_vector_type(4)));
typedef int   intx8  __attribute__((ext_vector_type(8)));
typedef float floatx4 __attribute__((ext_vector_type(4)));

// ---------------------------------------------------------------------------
// Kernel PREP (fused): blocks [0,NPATCH) = per-patch pooled embedding -> fp8
// e4m3 + ||e_q||^2 + psbits seed; blocks [NPATCH, ...) = memory_bank fp32 ->
// fp8 + ||m_q||^2 (4 rows/block, one wave/row).
// ---------------------------------------------------------------------------
__global__ __launch_bounds__(256) void prep_kernel(
    const float* __restrict__ f6, const float* __restrict__ f8,
    const float* __restrict__ f10, const float* __restrict__ mb,
    uint8_t* __restrict__ emb, float* __restrict__ enorm,
    uint8_t* __restrict__ mq, float* __restrict__ mnorm,
    int* __restrict__ psbits)
{
    __shared__ float pooled[3*PRE];   // 12 KB (emb half only)
    __shared__ float red[4];
    const int t = threadIdx.x;

    if (blockIdx.x < NPATCH) {
        // ---- embedding half ----
        const int n   = blockIdx.x;
        const int b   = n / (GRID_*GRID_);
        const int yx  = n - b*(GRID_*GRID_);
        const int y   = yx / GRID_;
        const int x   = yx - y*GRID_;

        if (t == 0) psbits[n] = 0x7f7f7f7f;   // +huge float bits for atomicMin

        const float* fl[3] = {f6, f8, f10};
#pragma unroll
        for (int l = 0; l < 3; ++l) {
            const float* f = fl[l];
            float A0 = 0.f, B0 = 0.f, C1 = 0.f, D1 = 0.f, E2 = 0.f, F2 = 0.f;
#pragma unroll
            for (int k = 0; k < 9; ++k) {
                const int kh = k / 3, kw = k - kh*3;
                const int ny = y + kh - 1, nx = x + kw - 1;
                const bool v = (ny >= 0 && ny < GRID_ && nx >= 0 && nx < GRID_);
                const int off = v ? (b*SEQ + 1 + ny*GRID_ + nx) : (b*SEQ);
                const float* p = f + (size_t)off*C_ + 3*t;
                float a = p[0], bq = p[1], c = p[2];
                if (!v) { a = 0.f; bq = 0.f; c = 0.f; }
                if (k <= 6) A0 += a;
                if (k >= 6) B0 += a;
                if (k <= 4) C1 += bq;
                if (k >= 4) D1 += bq;
                if (k <= 2) E2 += c;
                if (k >= 2) F2 += c;
            }
            float4 pv;
            pv.x = A0 * (1.f/7.f);
            pv.y = (B0 + C1) * (1.f/8.f);
            pv.z = (D1 + E2) * (1.f/8.f);
            pv.w = F2 * (1.f/7.f);
            *(float4*)(pooled + l*PRE + 4*t) = pv;
        }
        __syncthreads();

        // Aggregator + fp8 quantization; norm from QUANTIZED values so that
        // d2 = ||e_q||^2 + ||m_q||^2 - 2 e_q.m_q == ||e_q - m_q||^2 exactly
        float psq = 0.f;
        unsigned ob = 0;
#pragma unroll
        for (int r = 0; r < 4; ++r) {
            const int j = 4*t + r;
            float vv = (pooled[3*j] + pooled[3*j+1] + pooled[3*j+2]) * (1.f/3.f);
            __hip_fp8_e4m3 q(vv);
            ob |= ((unsigned)q.__x) << (8*r);
            float dq = (float)q;
            psq += dq*dq;
        }
        *(unsigned*)(emb + (size_t)n*TGT + 4*t) = ob;

        for (int off = 32; off > 0; off >>= 1) psq += __shfl_down(psq, off, 64);
        if ((t & 63) == 0) red[t >> 6] = psq;
        __syncthreads();
        if (t == 0) enorm[n] = (red[0] + red[1]) + (red[2] + red[3]);
    } else {
        // ---- memory-bank half ----
        const int r = (blockIdx.x - NPATCH)*4 + (t >> 6);
        const int l = t & 63;
        float psq = 0.f;
        unsigned ow[4];
        if (r < NMEM) {
            const float4* src = (const float4*)(mb + (size_t)r*TGT) + l*4;
#pragma unroll
            for (int i = 0; i < 4; ++i) {
                float4 v = src[i];
                __hip_fp8_e4m3 q0(v.x), q1(v.y), q2(v.z), q3(v.w);
                ow[i] = (unsigned)q0.__x | ((unsigned)q1.__x << 8)
                      | ((unsigned)q2.__x << 16) | ((unsigned)q3.__x << 24);
                float d0 = (float)q0, d1 = (float)q1, d2 = (float)q2, d3 = (float)q3;
                psq += d0*d0 + d1*d1 + d2*d2 + d3*d3;
            }
        } else {
            ow[0] = ow[1] = ow[2] = ow[3] = 0u;
        }
        *(uint4*)(mq + (size_t)r*TGT + l*16) = make_uint4(ow[0], ow[1], ow[2], ow[3]);

        for (int off = 32; off > 0; off >>= 1) psq += __shfl_down(psq, off, 64);
        if (l == 0) mnorm[r] = (r < NMEM) ? psq : 1e30f;
    }
}

// ---------------------------------------------------------------------------
// Kernel B: fused fp8 GEMM + min.  MX-scaled MFMA 16x16x128, unit scales.
// 128x128 block tile, BK=128, XOR-swizzled LDS (16B chunk c of row r at
// slot c ^ (r&7)).
// v7: R5's 8-wave/64x32-tile decomposition (acc[4][2]=32 AGPR, b[2]=16,
// a=8) but NO __launch_bounds__. Evidence: R3 (no bounds) never spilled;
// R4/R5/R6 (any bounds) all spilled ~2 GB because the capped unified file
// is split ~evenly VGPR/AGPR, starving the 8-reg-aligned MX operand
// tuples. Let the allocator run free; expected ~100-130 total regs ->
// 1-2 blocks/CU (8-16 waves) vs R3's 4 waves.
// ---------------------------------------------------------------------------
__device__ __forceinline__ void load_lds16(const void* g, void* l)
{
    __builtin_amdgcn_global_load_lds(
        (__attribute__((address_space(1))) void*)g,
        (__attribute__((address_space(3))) void*)l, 16, 0, 0);
}

__device__ __forceinline__ intx8 read_frag(const uint8_t* base, int row, int g)
{
    const int s0 = (2*g) ^ (row & 7);                 // chunk 2g   -> slot s0
    const intx4 lo = *(const intx4*)(base + row*128 + s0*16);
    const intx4 hi = *(const intx4*)(base + row*128 + (s0^1)*16); // chunk 2g+1
    intx8 r;
    r[0]=lo[0]; r[1]=lo[1]; r[2]=lo[2]; r[3]=lo[3];
    r[4]=hi[0]; r[5]=hi[1]; r[6]=hi[2]; r[7]=hi[3];
    return r;
}

__global__ void nnmin_kernel(
    const uint8_t* __restrict__ E, const uint8_t* __restrict__ M,
    const float* __restrict__ enorm, const float* __restrict__ mnorm,
    int* __restrict__ out_min)
{
    __shared__ __attribute__((aligned(16))) uint8_t As[128*128];  // 16 KB
    __shared__ __attribute__((aligned(16))) uint8_t Bs[128*128];  // 16 KB

    const int m0   = blockIdx.x * 128;
    const int n0   = blockIdx.y * 128;
    const int tid  = threadIdx.x;
    const int wave = tid >> 6;        // 0..7
    const int lane = tid & 63;
    const int wm   = wave >> 2;       // 0..1 : 64-row half
    const int wn   = wave & 3;        // 0..3 : 32-col quarter

    // staging: each wave stages 16 rows of A and 16 rows of B per K-iter,
    // in 2 calls of 8 rows each (64 lanes x 16B = 8 rows x 128B).
    const int sr8 = lane >> 3;                  // row within 8-row group
    const int sch = ((lane & 7) ^ sr8) * 16;    // swizzled global chunk
    const uint8_t* gA = E + (size_t)(m0 + wave*16 + sr8)*TGT + sch;
    const uint8_t* gB = M + (size_t)(n0 + wave*16 + sr8)*TGT + sch;
    uint8_t* lA = As + wave*16*128 + lane*16;
    uint8_t* lB = Bs + wave*16*128 + lane*16;

    floatx4 acc[4][2];
#pragma unroll
    for (int i = 0; i < 4; ++i)
#pragma unroll
        for (int j = 0; j < 2; ++j) acc[i][j] = (floatx4)0.0f;

    const int fr = lane & 15;       // fragment row within 16
    const int fg = lane >> 4;       // k-group: k = fg*32 + 0..31

    for (int k0 = 0; k0 < TGT; k0 += 128) {
        load_lds16(gA + k0, lA);
        load_lds16(gA + (size_t)8*TGT + k0, lA + 8*128);
        load_lds16(gB + k0, lB);
        load_lds16(gB + (size_t)8*TGT + k0, lB + 8*128);
        __syncthreads();

        intx8 b[2];
#pragma unroll
        for (int tn = 0; tn < 2; ++tn)
            b[tn] = read_frag(Bs, wn*32 + tn*16 + fr, fg);
#pragma unroll
        for (int tm = 0; tm < 4; ++tm) {
            const intx8 a = read_frag(As, wm*64 + tm*16 + fr, fg);
#pragma unroll
            for (int tn = 0; tn < 2; ++tn)
                acc[tm][tn] = __builtin_amdgcn_mfma_scale_f32_16x16x128_f8f6f4(
                    a, b[tn], acc[tm][tn],
                    0 /*cbsz: A=fp8*/, 0 /*blgp: B=fp8*/,
                    0, 0x7f7f7f7f /*scale_a = 1.0*/,
                    0, 0x7f7f7f7f /*scale_b = 1.0*/);
        }
        __syncthreads();
    }

    // epilogue: d2 + min over this block's 128 columns, atomicMin per row
    const int col  = lane & 15;
    const int rowq = (lane >> 4) * 4;
    const int colbase = n0 + wn*32;
    float mn[2];
#pragma unroll
    for (int tn = 0; tn < 2; ++tn) mn[tn] = mnorm[colbase + tn*16 + col];
#pragma unroll
    for (int tm = 0; tm < 4; ++tm) {
        const floatx4 en4 = *(const floatx4*)(enorm + m0 + wm*64 + tm*16 + rowq);
#pragma unroll
        for (int r = 0; r < 4; ++r) {
            float en = en4[r];
            float best = 1e38f;
#pragma unroll
            for (int tn = 0; tn < 2; ++tn) {
                float d2 = en + mn[tn] - 2.0f * acc[tm][tn][r];
                best = fminf(best, d2);
            }
#pragma unroll
            for (int off = 1; off < 16; off <<= 1)
                best = fminf(best, __shfl_xor(best, off, 64));
            if (col == 0)
                atomicMin(&out_min[m0 + wm*64 + tm*16 + rowq + r],
                          __float_as_int(best));
        }
    }
}

// ---------------------------------------------------------------------------
// Kernel POST (fused): blocks [0,4608) = bilinear 24->384 mask upsample
// (jax half-pixel == clamped bilinear); blocks [4608,4616) = per-image max.
// ---------------------------------------------------------------------------
__global__ __launch_bounds__(256) void post_kernel(
    const int* __restrict__ ps_bits, float* __restrict__ scores,
    float* __restrict__ masks)
{
    if (blockIdx.x < (B_*IMG_*IMG_)/256) {
        int idx = blockIdx.x*256 + threadIdx.x;
        int b  = idx / (IMG_*IMG_);
        int p  = idx - b*(IMG_*IMG_);
        int oy = p / IMG_, ox = p - oy*IMG_;

        float fy = (oy + 0.5f) * (1.0f/16.0f) - 0.5f;
        float fx = (ox + 0.5f) * (1.0f/16.0f) - 0.5f;
        int y0 = (int)floorf(fy); float ty = fy - (float)y0;
        int x0 = (int)floorf(fx); float tx = fx - (float)x0;
        int y0c = min(max(y0, 0), GRID_-1), y1c = min(max(y0+1, 0), GRID_-1);
        int x0c = min(max(x0, 0), GRID_-1), x1c = min(max(x0+1, 0), GRID_-1);

        const int* psb = ps_bits + b*GRID_*GRID_;
        float v00 = __int_as_float(psb[y0c*GRID_ + x0c]);
        float v01 = __int_as_float(psb[y0c*GRID_ + x1c]);
        float v10 = __int_as_float(psb[y1c*GRID_ + x0c]);
        float v11 = __int_as_float(psb[y1c*GRID_ + x1c]);
        float v0 = v00 + (v01 - v00)*tx;
        float v1 = v10 + (v11 - v10)*tx;
        masks[idx] = v0 + (v1 - v0)*ty;
    } else {
        const int b = blockIdx.x - (B_*IMG_*IMG_)/256;
        const int tid = threadIdx.x;
        __shared__ float red[4];
        float m = -1e38f;
        for (int i = tid; i < GRID_*GRID_; i += 256)
            m = fmaxf(m, __int_as_float(ps_bits[b*GRID_*GRID_ + i]));
        for (int off = 32; off > 0; off >>= 1)
            m = fmaxf(m, __shfl_down(m, off, 64));
        if ((tid & 63) == 0) red[tid >> 6] = m;
        __syncthreads();
        if (tid == 0)
            scores[b] = fmaxf(fmaxf(red[0], red[1]), fmaxf(red[2], red[3]));
    }
}

// ---------------------------------------------------------------------------
extern "C" void kernel_launch(void* const* d_in, const int* in_sizes, int n_in,
                              void* d_out, int out_size, void* d_ws, size_t ws_size,
                              hipStream_t stream)
{
    const float* f6  = (const float*)d_in[0];
    const float* f8  = (const float*)d_in[1];
    const float* f10 = (const float*)d_in[2];
    const float* mb  = (const float*)d_in[3];
    float* out = (float*)d_out;

    char* ws = (char*)d_ws;
    uint8_t* emb = (uint8_t*)ws; ws += (size_t)NPATCH*TGT;       // 4.7 MB
    uint8_t* mq  = (uint8_t*)ws; ws += (size_t)NMEM_PAD*TGT;     // 20.6 MB
    float* enorm = (float*)ws;   ws += (size_t)NPATCH*sizeof(float);
    float* mnorm = (float*)ws;   ws += (size_t)NMEM_PAD*sizeof(float);
    int* psbits  = (int*)ws;     ws += (size_t)NPATCH*sizeof(int);

    hipLaunchKernelGGL(prep_kernel, dim3(NPATCH + NMEM_PAD/4), dim3(256), 0,
                       stream, f6, f8, f10, mb, emb, enorm, mq, mnorm, psbits);
    hipLaunchKernelGGL(nnmin_kernel, dim3(NPATCH/128, NMEM_PAD/128), dim3(512),
                       0, stream, emb, mq, enorm, mnorm, psbits);
    hipLaunchKernelGGL(post_kernel, dim3((B_*IMG_*IMG_)/256 + B_), dim3(256),
                       0, stream, psbits, out, out + B_);
}